// Round 9
// baseline (310.416 us; speedup 1.0000x reference)
//
#include <hip/hip_runtime.h>
#include <hip/hip_bf16.h>

// B=32, C=32, H=W=256, regions 4x4 of 64x64.
// Round 9: ring-buffer pipelined conv (r7 idea, spill-safe rebuild).
// Block = (b, p, 32-row half). LDS ring = 8 rows x 64 cols x 32 ch bf16
// (32KB). Per 4-row tile: A[issue loads rows q+5..q+8 | compute rows q,q+1]
// barrier, B[ds-write pending | compute rows q+2,q+3] barrier.
// Weights in VGPRs (72) so the MFMA loop touches no vmcnt counters.
// r7 lessons: no tight launch_bounds (spills), no global loads in MFMA loop.

#define EPS 1e-5f

typedef float f32x4 __attribute__((ext_vector_type(4)));
typedef __bf16 bf16x8 __attribute__((ext_vector_type(8)));
typedef short short8 __attribute__((ext_vector_type(8)));

__device__ inline short f2bf(float f) {
  union { __hip_bfloat16 h; short s; } u;
  u.h = __float2bfloat16(f);
  return u.s;
}

// ---------------- Kernel 1: per-(b,c) plane stats, contiguous sweep ----------
__global__ __launch_bounds__(256) void stats_partial(
    const float* __restrict__ x, float* __restrict__ ws_sum,
    float* __restrict__ ws_sq) {
  int plane = blockIdx.x;            // b*32 + c
  const float* base = x + (size_t)plane * 65536;
  int t = threadIdx.x;
  float s[4] = {0.f, 0.f, 0.f, 0.f}, q[4] = {0.f, 0.f, 0.f, 0.f};
#pragma unroll
  for (int R = 0; R < 4; ++R) {
#pragma unroll
    for (int ii = 0; ii < 16; ++ii) {
      int idx4 = (R * 16 + ii) * 256 + t;     // float4 index
      float4 v = *reinterpret_cast<const float4*>(base + (size_t)idx4 * 4);
      s[R] += (v.x + v.y) + (v.z + v.w);
      q[R] += (v.x * v.x + v.y * v.y) + (v.z * v.z + v.w * v.w);
    }
  }
#pragma unroll
  for (int R = 0; R < 4; ++R) {
#pragma unroll
    for (int off = 8; off; off >>= 1) {
      s[R] += __shfl_down(s[R], off);
      q[R] += __shfl_down(q[R], off);
    }
  }
  __shared__ float red[2][4][4][4];  // [s|q][wave][Cc][R]
  int lane = t & 63, wv = t >> 6;
  if ((lane & 15) == 0) {
    int Cc = lane >> 4;
#pragma unroll
    for (int R = 0; R < 4; ++R) {
      red[0][wv][Cc][R] = s[R];
      red[1][wv][Cc][R] = q[R];
    }
  }
  __syncthreads();
  if (t < 16) {                      // t == p
    int R = t >> 2, Cc = t & 3;
    float S = 0.f, Q = 0.f;
#pragma unroll
    for (int w = 0; w < 4; ++w) {
      S += red[0][w][Cc][R];
      Q += red[1][w][Cc][R];
    }
    ws_sum[plane * 16 + t] = S;
    ws_sq[plane * 16 + t] = Q;
  }
}

// ---------------- Kernel 2: pack conv_w into MFMA A-fragments ----------------
__global__ __launch_bounds__(256) void weights_prep(
    const float* __restrict__ conv_w, unsigned short* __restrict__ wfrag) {
  int idx = blockIdx.x * 256 + threadIdx.x;
  if (idx >= 18 * 64) return;
  int lane = idx & 63;
  int th = idx >> 6;                 // t*2 + h
  int t = th >> 1, h = th & 1;
  int dy = t / 3, dx = t - dy * 3;
  int oc = h * 16 + (lane & 15);
  int ic0 = (lane >> 4) * 8;
#pragma unroll
  for (int j = 0; j < 8; ++j) {
    float w = conv_w[((oc * 32 + ic0 + j) * 3 + dy) * 3 + dx];
    wfrag[(size_t)idx * 8 + j] = (unsigned short)f2bf(w);
  }
}

// ---------------- Kernel 3: ring-pipelined finalize + norm/prelu + conv -----
// 1024 blocks x 256 threads = (b, p, h). Rows r0..r0+31, r0 = h*32.
// LDS ring[8][64][32] bf16, slot = row & 7, ic-slot swizzle (s+(col>>1))&3.
__global__ __launch_bounds__(256, 3) void conv_ring(
    const float* __restrict__ x, const unsigned short* __restrict__ wfrag,
    const float* __restrict__ conv_b, const float* __restrict__ prelu_a,
    const float* __restrict__ ws_sum, const float* __restrict__ ws_sq,
    const float* __restrict__ gamma, const float* __restrict__ beta,
    float* __restrict__ out) {
  __shared__ short ring[8 * 64 * 32];   // 32768 B

  int blk = blockIdx.x;              // b*32 + p*2 + h
  int h = blk & 1;
  int p = (blk >> 1) & 15;
  int b = blk >> 5;
  int R = p >> 2, Cc = p & 3;
  int r0 = h * 32;
  int tid = threadIdx.x;
  int lane = tid & 63;
  float pa = prelu_a[0];

  // ---- local finalize: per-channel scale/shift for region p (32 threads)
  float* abuf = (float*)ring;        // [0..31]=a, [32..63]=b; freed below
  if (tid < 32) {
    int c = tid;
    float S = 0.f, Q = 0.f;
#pragma unroll
    for (int bb = 0; bb < 32; ++bb) {
      int idx = (bb * 32 + c) * 16 + p;
      S += ws_sum[idx];
      Q += ws_sq[idx];
    }
    const float inv = 1.0f / 131072.0f;
    float mean = S * inv;
    float var = Q * inv - mean * mean;
    float rstd = rsqrtf(var + EPS);
    float a = rstd * gamma[c];
    abuf[c] = a;
    abuf[32 + c] = beta[c] - mean * a;
  }
  __syncthreads();

  // per-thread-fixed staging decomposition: (row=srb, ic-slice=s, col-quad=c4)
  int s = (tid >> 4) & 3;
  int c4 = tid & 15;
  int srb = tid >> 6;                // 0..3
  int ic0 = s * 8;

  float a_r[8], b_r[8];
#pragma unroll
  for (int j = 0; j < 8; ++j) {
    a_r[j] = abuf[ic0 + j];
    b_r[j] = abuf[32 + ic0 + j];
  }
  __syncthreads();                   // abuf consumed; ring free

  // ---- staging helpers (lr = region-local row, may be OOB -> zeros)
  auto stage_load = [&](f32x4(&vv)[8], int lr) {
#pragma unroll
    for (int kk = 0; kk < 8; ++kk) vv[kk] = f32x4{0.f, 0.f, 0.f, 0.f};
    if ((unsigned)lr < 64u) {
      const float* xp =
          x + (((size_t)(b * 32 + ic0) * 256 + R * 64 + lr) * 256) + Cc * 64 +
          c4 * 4;
#pragma unroll
      for (int kk = 0; kk < 8; ++kk)
        vv[kk] = *reinterpret_cast<const f32x4*>(xp + (size_t)kk * 65536);
    }
  };
  auto stage_write = [&](const f32x4(&vv)[8], int lr) {
    int srl = lr & 7;
#pragma unroll
    for (int j = 0; j < 4; ++j) {
      short8 pk;
#pragma unroll
      for (int kk = 0; kk < 8; ++kk) {
        float e = fmaf(a_r[kk], vv[kk][j], b_r[kk]);
        e = e > 0.f ? e : pa * e;
        pk[kk] = f2bf(e);
      }
      int col = c4 * 4 + j;
      int slot = (s + (col >> 1)) & 3;
      *reinterpret_cast<short8*>(&ring[(srl * 64 + col) * 32 + slot * 8]) = pk;
    }
  };

  // ---- prologue: stage rows r0-1 .. r0+4 (slots 7,0,1,2,3,4)
  {
    f32x4 v[8];
    int lr1 = r0 - 1 + srb;          // r0-1..r0+2
    stage_load(v, lr1);
    stage_write(v, lr1);
    if (tid < 128) {
      int lr2 = r0 + 3 + srb;        // srb in {0,1} -> r0+3, r0+4
      stage_load(v, lr2);
      stage_write(v, lr2);
    }
  }

  // ---- weight fragments + bias (VGPR-resident: MFMA loop has no vmem)
  bf16x8 wf[18];
#pragma unroll
  for (int th = 0; th < 18; ++th) {
    short8 sv =
        *reinterpret_cast<const short8*>(wfrag + ((size_t)th * 64 + lane) * 8);
    wf[th] = __builtin_bit_cast(bf16x8, sv);
  }
  int l15 = lane & 15, l4 = lane >> 4;
  f32x4 bias0, bias1;
#pragma unroll
  for (int i = 0; i < 4; ++i) {
    bias0[i] = conv_b[l4 * 4 + i];
    bias1[i] = conv_b[16 + l4 * 4 + i];
  }
  int wv = tid >> 6;
  const short8 z8 = {0, 0, 0, 0, 0, 0, 0, 0};
  __syncthreads();

  // ---- compute 2 rows (q+ph*2, q+ph*2+1), 2 groups per wave
  auto compute_phase = [&](int q, int ph) {
#pragma unroll
    for (int g = 0; g < 2; ++g) {
      int gi = wv * 2 + g;           // 0..7
      int rowloc = q + ph * 2 + (gi >> 2);
      int c0 = (gi & 3) * 16;
      f32x4 acc0 = bias0, acc1 = bias1;
#pragma unroll
      for (int t9 = 0; t9 < 9; ++t9) {
        const int dy = t9 / 3, dx = t9 - dy * 3;
        int srl = (rowloc + dy - 1) & 7;
        int col_in = c0 + l15 + dx - 1;
        int colc = col_in & 63;
        int slot = (l4 + (colc >> 1)) & 3;
        short8 sv = *reinterpret_cast<const short8*>(
            &ring[(srl * 64 + colc) * 32 + slot * 8]);
        if (dx == 0 && c0 == 0 && l15 == 0) sv = z8;    // col -1 zero pad
        if (dx == 2 && c0 == 48 && l15 == 15) sv = z8;  // col 64 zero pad
        bf16x8 bv = __builtin_bit_cast(bf16x8, sv);
        acc0 = __builtin_amdgcn_mfma_f32_16x16x32_bf16(wf[t9 * 2], bv, acc0,
                                                       0, 0, 0);
        acc1 = __builtin_amdgcn_mfma_f32_16x16x32_bf16(wf[t9 * 2 + 1], bv,
                                                       acc1, 0, 0, 0);
      }
      int grow = R * 64 + rowloc;
      int gcol = Cc * 64 + c0 + l15;
      float* ob = out + (size_t)b * 2097152 + (size_t)grow * 256 + gcol;
#pragma unroll
      for (int i = 0; i < 4; ++i) {
        ob[(size_t)(l4 * 4 + i) * 65536] = acc0[i];
        ob[(size_t)(16 + l4 * 4 + i) * 65536] = acc1[i];
      }
    }
  };

  // ---- main loop: 8 tiles of 4 rows
  for (int t = 0; t < 8; ++t) {
    int q = r0 + t * 4;
    bool pre = (t < 7);
    f32x4 pend[8];
    int prow = q + 5 + srb;          // rows q+5..q+8 across srb
    if (pre) stage_load(pend, prow); // loads in flight across phase A
    compute_phase(q, 0);             // rows q, q+1 (reads q-1..q+2)
    __syncthreads();
    if (pre) stage_write(pend, prow);   // slots {5,6,7,0}+4t
    compute_phase(q, 1);             // rows q+2,q+3 (reads q+1..q+4: {1..4})
    __syncthreads();
  }
}

extern "C" void kernel_launch(void* const* d_in, const int* in_sizes, int n_in,
                              void* d_out, int out_size, void* d_ws,
                              size_t ws_size, hipStream_t stream) {
  const float* x = (const float*)d_in[0];
  const float* gamma = (const float*)d_in[1];
  const float* beta = (const float*)d_in[2];
  const float* prelu_a = (const float*)d_in[3];
  const float* conv_w = (const float*)d_in[4];
  const float* conv_b = (const float*)d_in[5];
  float* out = (float*)d_out;

  float* ws = (float*)d_ws;
  float* ws_sum = ws;                          // 16384 floats
  float* ws_sq = ws + 16384;                   // 16384
  unsigned short* wfrag = (unsigned short*)(ws + 32768);   // 18*64*8 shorts

  weights_prep<<<5, 256, 0, stream>>>(conv_w, wfrag);
  stats_partial<<<1024, 256, 0, stream>>>(x, ws_sum, ws_sq);
  conv_ring<<<1024, 256, 0, stream>>>(x, wfrag, conv_b, prelu_a, ws_sum, ws_sq,
                                      gamma, beta, out);
}

// Round 10
// 205.333 us; speedup vs baseline: 1.5118x; 1.5118x over previous
//
#include <hip/hip_runtime.h>
#include <hip/hip_bf16.h>

// B=32, C=32, H=W=256, regions 4x4 of 64x64.
// Round 10: r8 skeleton, conv tile shrunk to 4 output rows (6 staged rows,
// LDS 24KB -> 6 blocks/CU, 24 waves/CU) for phase-interleave TLP. Plain
// __launch_bounds__(256) only (r7/r9 lesson: min-waves hint => VGPR throttle
// => scratch spills). Stats split to 2048 half-plane blocks.

#define EPS 1e-5f

typedef float f32x4 __attribute__((ext_vector_type(4)));
typedef __bf16 bf16x8 __attribute__((ext_vector_type(8)));
typedef short short8 __attribute__((ext_vector_type(8)));

__device__ inline short f2bf(float f) {
  union { __hip_bfloat16 h; short s; } u;
  u.h = __float2bfloat16(f);
  return u.s;
}

// ---------------- Kernel 1: per-(b,c) half-plane stats ----------
// 2048 blocks: plane = blk>>1, half = blk&1 covers R in {2h, 2h+1}.
__global__ __launch_bounds__(256) void stats_partial(
    const float* __restrict__ x, float* __restrict__ ws_sum,
    float* __restrict__ ws_sq) {
  int blk = blockIdx.x;
  int plane = blk >> 1;              // b*32 + c
  int half = blk & 1;
  const float* base = x + (size_t)plane * 65536 + (size_t)half * 32768;
  int t = threadIdx.x;
  float s[2] = {0.f, 0.f}, q[2] = {0.f, 0.f};
#pragma unroll
  for (int Rl = 0; Rl < 2; ++Rl) {
#pragma unroll
    for (int ii = 0; ii < 16; ++ii) {
      int idx4 = (Rl * 16 + ii) * 256 + t;    // float4 index within half
      float4 v = *reinterpret_cast<const float4*>(base + (size_t)idx4 * 4);
      s[Rl] += (v.x + v.y) + (v.z + v.w);
      q[Rl] += (v.x * v.x + v.y * v.y) + (v.z * v.z + v.w * v.w);
    }
  }
#pragma unroll
  for (int Rl = 0; Rl < 2; ++Rl) {
#pragma unroll
    for (int off = 8; off; off >>= 1) {
      s[Rl] += __shfl_down(s[Rl], off);
      q[Rl] += __shfl_down(q[Rl], off);
    }
  }
  __shared__ float red[2][4][4][2];  // [s|q][wave][Cc][Rl]
  int lane = t & 63, wv = t >> 6;
  if ((lane & 15) == 0) {
    int Cc = lane >> 4;
#pragma unroll
    for (int Rl = 0; Rl < 2; ++Rl) {
      red[0][wv][Cc][Rl] = s[Rl];
      red[1][wv][Cc][Rl] = q[Rl];
    }
  }
  __syncthreads();
  if (t < 8) {                       // Rl = t>>2, Cc = t&3
    int Rl = t >> 2, Cc = t & 3;
    float S = 0.f, Q = 0.f;
#pragma unroll
    for (int w = 0; w < 4; ++w) {
      S += red[0][w][Cc][Rl];
      Q += red[1][w][Cc][Rl];
    }
    int p = (half * 2 + Rl) * 4 + Cc;
    ws_sum[plane * 16 + p] = S;
    ws_sq[plane * 16 + p] = Q;
  }
}

// ---------------- Kernel 2: pack conv_w into MFMA A-fragments ----------------
__global__ __launch_bounds__(256) void weights_prep(
    const float* __restrict__ conv_w, unsigned short* __restrict__ wfrag) {
  int idx = blockIdx.x * 256 + threadIdx.x;
  if (idx >= 18 * 64) return;
  int lane = idx & 63;
  int th = idx >> 6;                 // t*2 + h
  int t = th >> 1, h = th & 1;
  int dy = t / 3, dx = t - dy * 3;
  int oc = h * 16 + (lane & 15);
  int ic0 = (lane >> 4) * 8;
#pragma unroll
  for (int j = 0; j < 8; ++j) {
    float w = conv_w[((oc * 32 + ic0 + j) * 3 + dy) * 3 + dx];
    wfrag[(size_t)idx * 8 + j] = (unsigned short)f2bf(w);
  }
}

// ---------------- Kernel 3: finalize + normalize+prelu -> LDS -> MFMA -------
// block = (b, p, rt): 4 output rows x 64 cols. 4 waves. LDS [6][64][32] bf16
// = 24576 B -> 6 blocks/CU. slot swizzle (s + (col>>1)) & 3.
__global__ __launch_bounds__(256) void conv_mfma(
    const float* __restrict__ x, const unsigned short* __restrict__ wfrag,
    const float* __restrict__ conv_b, const float* __restrict__ prelu_a,
    const float* __restrict__ ws_sum, const float* __restrict__ ws_sq,
    const float* __restrict__ gamma, const float* __restrict__ beta,
    float* __restrict__ out) {
  __shared__ short lds_y[6 * 64 * 32];   // 24576 B

  int blk0 = blockIdx.x;             // 8192 blocks; chunked XCD swizzle
  int blk = (blk0 & 7) * 1024 + (blk0 >> 3);
  int rt = blk & 15;
  int p = (blk >> 4) & 15;
  int b = blk >> 8;
  int R = p >> 2, Cc = p & 3;
  int h0 = rt * 4;
  int tid = threadIdx.x;
  int lane = tid & 63;
  float pa = prelu_a[0];

  // ---- local finalize: per-channel scale/shift for region p (32 threads)
  float* abuf = (float*)lds_y;       // [0..31]=a, [32..63]=b; freed below
  if (tid < 32) {
    int c = tid;
    float S = 0.f, Q = 0.f;
#pragma unroll
    for (int bb = 0; bb < 32; ++bb) {
      int idx = (bb * 32 + c) * 16 + p;
      S += ws_sum[idx];
      Q += ws_sq[idx];
    }
    const float inv = 1.0f / 131072.0f;
    float mean = S * inv;
    float var = Q * inv - mean * mean;
    float rstd = rsqrtf(var + EPS);
    float a = rstd * gamma[c];
    abuf[c] = a;
    abuf[32 + c] = beta[c] - mean * a;
  }
  __syncthreads();

  // per-thread-fixed staging decomposition
  int s = (tid >> 4) & 3;            // ic-slice
  int c4 = tid & 15;                 // col-quad
  int srb = tid >> 6;                // base staged-row 0..3
  int ic0 = s * 8;

  float a_r[8], b_r[8];
#pragma unroll
  for (int j = 0; j < 8; ++j) {
    a_r[j] = abuf[ic0 + j];
    b_r[j] = abuf[32 + ic0 + j];
  }
  __syncthreads();                   // abuf consumed; LDS free for staging

  // ---- staging helpers
  auto stage_load = [&](f32x4(&vv)[8], int sr) {
    int lr = h0 - 1 + sr;
#pragma unroll
    for (int kk = 0; kk < 8; ++kk) vv[kk] = f32x4{0.f, 0.f, 0.f, 0.f};
    if ((unsigned)lr < 64u) {
      const float* xp =
          x + (((size_t)(b * 32 + ic0) * 256 + R * 64 + lr) * 256) + Cc * 64 +
          c4 * 4;
#pragma unroll
      for (int kk = 0; kk < 8; ++kk)
        vv[kk] = *reinterpret_cast<const f32x4*>(xp + (size_t)kk * 65536);
    }
  };
  auto stage_write = [&](const f32x4(&vv)[8], int sr) {
#pragma unroll
    for (int j = 0; j < 4; ++j) {
      short8 pk;
#pragma unroll
      for (int kk = 0; kk < 8; ++kk) {
        float e = fmaf(a_r[kk], vv[kk][j], b_r[kk]);
        e = e > 0.f ? e : pa * e;
        pk[kk] = f2bf(e);
      }
      int col = c4 * 4 + j;
      int slot = (s + (col >> 1)) & 3;
      *reinterpret_cast<short8*>(&lds_y[(sr * 64 + col) * 32 + slot * 8]) = pk;
    }
  };

  // ---- 2-deep pipelined staging: rows srb (all), 4+srb (tid<128)
  {
    f32x4 va[8], vb[8];
    stage_load(va, srb);             // 8 loads in flight
    if (tid < 128) stage_load(vb, 4 + srb);   // +8 more for half the threads
    stage_write(va, srb);
    if (tid < 128) stage_write(vb, 4 + srb);
  }
  __syncthreads();

  // ---- weight fragments + bias (post-barrier)
  bf16x8 wf[18];
#pragma unroll
  for (int th = 0; th < 18; ++th) {
    short8 sv =
        *reinterpret_cast<const short8*>(wfrag + ((size_t)th * 64 + lane) * 8);
    wf[th] = __builtin_bit_cast(bf16x8, sv);
  }
  int l15 = lane & 15, l4 = lane >> 4;
  f32x4 bias0, bias1;
#pragma unroll
  for (int i = 0; i < 4; ++i) {
    bias0[i] = conv_b[l4 * 4 + i];
    bias1[i] = conv_b[16 + l4 * 4 + i];
  }

  // ---- MFMA: each wave does 4 groups (16 groups = 4 rows x 4 col-blocks)
  int wv = tid >> 6;
  const short8 z8 = {0, 0, 0, 0, 0, 0, 0, 0};
  for (int g = 0; g < 4; ++g) {
    int gi = wv * 4 + g;
    int r = gi >> 2;                 // 0..3
    int c0 = (gi & 3) * 16;
    f32x4 acc0 = bias0, acc1 = bias1;
#pragma unroll
    for (int t9 = 0; t9 < 9; ++t9) {
      const int dy = t9 / 3, dx = t9 - dy * 3;
      int sr = r + dy;               // 0..5
      int col_in = c0 + l15 + dx - 1;
      int colc = col_in & 63;
      int slot = (l4 + (colc >> 1)) & 3;
      short8 sv = *reinterpret_cast<const short8*>(
          &lds_y[(sr * 64 + colc) * 32 + slot * 8]);
      if (dx == 0) {
        if (c0 == 0 && l15 == 0) sv = z8;     // col -1 -> zero pad
      }
      if (dx == 2) {
        if (c0 == 48 && l15 == 15) sv = z8;   // col 64 -> zero pad
      }
      bf16x8 bv = __builtin_bit_cast(bf16x8, sv);
      acc0 = __builtin_amdgcn_mfma_f32_16x16x32_bf16(wf[t9 * 2], bv, acc0, 0, 0, 0);
      acc1 = __builtin_amdgcn_mfma_f32_16x16x32_bf16(wf[t9 * 2 + 1], bv, acc1, 0, 0, 0);
    }
    int grow = R * 64 + h0 + r;
    int gcol = Cc * 64 + c0 + l15;
    float* ob = out + (size_t)b * 2097152 + (size_t)grow * 256 + gcol;
#pragma unroll
    for (int i = 0; i < 4; ++i) {
      ob[(size_t)(l4 * 4 + i) * 65536] = acc0[i];
      ob[(size_t)(16 + l4 * 4 + i) * 65536] = acc1[i];
    }
  }
}

extern "C" void kernel_launch(void* const* d_in, const int* in_sizes, int n_in,
                              void* d_out, int out_size, void* d_ws,
                              size_t ws_size, hipStream_t stream) {
  const float* x = (const float*)d_in[0];
  const float* gamma = (const float*)d_in[1];
  const float* beta = (const float*)d_in[2];
  const float* prelu_a = (const float*)d_in[3];
  const float* conv_w = (const float*)d_in[4];
  const float* conv_b = (const float*)d_in[5];
  float* out = (float*)d_out;

  float* ws = (float*)d_ws;
  float* ws_sum = ws;                          // 16384 floats
  float* ws_sq = ws + 16384;                   // 16384
  unsigned short* wfrag = (unsigned short*)(ws + 32768);   // 18*64*8 shorts

  weights_prep<<<5, 256, 0, stream>>>(conv_w, wfrag);
  stats_partial<<<2048, 256, 0, stream>>>(x, ws_sum, ws_sq);
  conv_mfma<<<8192, 256, 0, stream>>>(x, wfrag, conv_b, prelu_a, ws_sum, ws_sq,
                                      gamma, beta, out);
}